// Round 2
// baseline (654.001 us; speedup 1.0000x reference)
//
#include <hip/hip_runtime.h>

#define ENT 200
#define RELD 200
#define NREL 1000
#define NBATCH 16384
#define MARGIN 4.0f
#define CHUNK 16       // items per block
#define NVEC 64        // CHUNK*4 vectors staged per block
#define MAXCHUNKS 2048 // >= 16384/16 + 1000 = 2024
#define SVPAD 68       // row stride for sv: %4==0 (float4 align), %32==4 (8-way write conflict only)

// ---- workspace layout (int units) ----
#define WS_COUNTS 0        // [1024]
#define WS_CURSORS 1024    // [1024]
#define WS_OFFSETS 2048    // [1024]
#define WS_NCHUNKS 3072    // [4]
#define WS_CHUNKS 3076     // int4[2048] -> 8192 ints (byte off 12304, 16B aligned)
#define WS_LIST 11268      // [16384]
#define WS_ELEM 27652      // float[16384]

__device__ __forceinline__ float wave_reduce(float v) {
#pragma unroll
    for (int off = 32; off > 0; off >>= 1) v += __shfl_down(v, off, 64);
    return v;
}

__global__ __launch_bounds__(1024) void zero_kernel(int* ws) {
    // zero counts, cursors, nchunks
    for (int i = threadIdx.x; i < 3076; i += 1024) ws[i] = 0;
}

__global__ __launch_bounds__(256) void count_kernel(const int* __restrict__ pos_r, int* ws) {
    const int i = blockIdx.x * 256 + threadIdx.x;
    if (i < NBATCH) atomicAdd(&ws[WS_COUNTS + pos_r[i]], 1);
}

// single block, 1024 threads: exclusive offsets + chunk descriptors
__global__ __launch_bounds__(1024) void scan_kernel(int* ws) {
    __shared__ int s[1024];
    const int tid = threadIdx.x;
    const int cnt = (tid < NREL) ? ws[WS_COUNTS + tid] : 0;
    s[tid] = cnt;
    __syncthreads();
#pragma unroll
    for (int off = 1; off < 1024; off <<= 1) {
        const int add = (tid >= off) ? s[tid - off] : 0;
        __syncthreads();
        s[tid] += add;
        __syncthreads();
    }
    const int myoff = s[tid] - cnt;  // exclusive item offset
    if (tid < NREL) ws[WS_OFFSETS + tid] = myoff;
    __syncthreads();
    const int nch = (cnt + CHUNK - 1) / CHUNK;
    s[tid] = nch;
    __syncthreads();
#pragma unroll
    for (int off = 1; off < 1024; off <<= 1) {
        const int add = (tid >= off) ? s[tid - off] : 0;
        __syncthreads();
        s[tid] += add;
        __syncthreads();
    }
    const int cbase = s[tid] - nch;  // exclusive chunk offset
    int4* chunks = (int4*)(ws + WS_CHUNKS);
    for (int k = 0; k < nch; ++k)
        chunks[cbase + k] = make_int4(tid, myoff + CHUNK * k, min(CHUNK, cnt - CHUNK * k), 0);
    if (tid == 1023) ws[WS_NCHUNKS] = s[1023];
}

__global__ __launch_bounds__(256) void fill_kernel(const int* __restrict__ pos_r, int* ws) {
    const int i = blockIdx.x * 256 + threadIdx.x;
    if (i < NBATCH) {
        const int r = pos_r[i];
        const int p = ws[WS_OFFSETS + r] + atomicAdd(&ws[WS_CURSORS + r], 1);
        ws[WS_LIST + p] = i;
    }
}

// One block per chunk: <=16 items sharing one relation matrix.
__global__ __launch_bounds__(256) void transr_chunk_kernel(
    const int* __restrict__ pos_h, const int* __restrict__ pos_t,
    const int* __restrict__ neg_h, const int* __restrict__ neg_t,
    const float* __restrict__ ent_emb, const float* __restrict__ rel_emb,
    const float* __restrict__ transfer, int* __restrict__ ws)
{
    const int nch = ws[WS_NCHUNKS];
    if ((int)blockIdx.x >= nch) return;

    __shared__ float sv[ENT][SVPAD];   // sv[e][item*4+c]
    __shared__ float sred[4][66];
    __shared__ float sinv[66];
    __shared__ float ssc[34];
    __shared__ int items_s[CHUNK];
    __shared__ int rows[NVEC];

    const int4 ck = ((const int4*)(ws + WS_CHUNKS))[blockIdx.x];
    const int r = ck.x, start = ck.y, cnt = ck.z;

    const int tid = threadIdx.x;
    const int lane = tid & 63;
    const int wv = tid >> 6;

    if (tid < CHUNK) items_s[tid] = ws[WS_LIST + start + min(tid, cnt - 1)];
    __syncthreads();
    if (tid < NVEC) {
        const int b = items_s[tid >> 2];
        const int c = tid & 3;
        rows[tid] = (c == 0) ? pos_h[b] : (c == 1) ? pos_t[b] : (c == 2) ? neg_h[b] : neg_t[b];
    }
    __syncthreads();

    // gather 64 embedding vectors: wave wv handles vectors wv, wv+4, ...
    for (int v = wv; v < NVEC; v += 4) {
        const float* __restrict__ src = ent_emb + (size_t)rows[v] * ENT;
#pragma unroll
        for (int k = 0; k < 4; ++k) {
            const int e = lane + 64 * k;
            if (e < ENT) sv[e][v] = src[e];
        }
    }
    const int jeff = min(tid, ENT - 1);
    const float srj = (tid < RELD) ? rel_emb[(size_t)r * RELD + tid] : 0.f;
    __syncthreads();

    // main loop: thread j owns M column j
    float acc[CHUNK][4];
#pragma unroll
    for (int i = 0; i < CHUNK; ++i)
#pragma unroll
        for (int c = 0; c < 4; ++c) acc[i][c] = 0.f;

    const float* __restrict__ Mcol = transfer + (size_t)r * (ENT * RELD) + jeff;
    for (int e = 0; e < ENT; ++e) {
        const float m = Mcol[(size_t)e * RELD];
        const float4* __restrict__ vrow = (const float4*)(&sv[e][0]);
#pragma unroll
        for (int i = 0; i < CHUNK; ++i) {
            const float4 v = vrow[i];
            acc[i][0] = fmaf(v.x, m, acc[i][0]);
            acc[i][1] = fmaf(v.y, m, acc[i][1]);
            acc[i][2] = fmaf(v.z, m, acc[i][2]);
            acc[i][3] = fmaf(v.w, m, acc[i][3]);
        }
    }
    if (tid >= RELD) {
#pragma unroll
        for (int i = 0; i < CHUNK; ++i)
#pragma unroll
            for (int c = 0; c < 4; ++c) acc[i][c] = 0.f;
    }

    // 64 projection norms + rel norm
#pragma unroll
    for (int t = 0; t < NVEC; ++t) {
        const float a = acc[t >> 2][t & 3];
        const float s = wave_reduce(a * a);
        if (lane == 0) sred[wv][t] = s;
    }
    {
        const float s = wave_reduce(srj * srj);
        if (lane == 0) sred[wv][64] = s;
    }
    __syncthreads();
    if (tid < 65) {
        const float tot = sred[0][tid] + sred[1][tid] + sred[2][tid] + sred[3][tid];
        sinv[tid] = rsqrtf(fmaxf(tot, 1e-12f));
    }
    __syncthreads();

    const float rterm = srj * sinv[64];
#pragma unroll
    for (int i = 0; i < CHUNK; ++i) {
        const float p = acc[i][0] * sinv[i * 4 + 0] + rterm - acc[i][1] * sinv[i * 4 + 1];
        const float n = acc[i][2] * sinv[i * 4 + 2] + rterm - acc[i][3] * sinv[i * 4 + 3];
        const float ps = wave_reduce(fabsf(p));
        const float ns = wave_reduce(fabsf(n));
        if (lane == 0) { sred[wv][i * 2] = ps; sred[wv][i * 2 + 1] = ns; }
    }
    __syncthreads();
    if (tid < 2 * CHUNK) {
        ssc[tid] = sred[0][tid] + sred[1][tid] + sred[2][tid] + sred[3][tid];
    }
    __syncthreads();
    if (tid < cnt) {
        float* elem = (float*)(ws + WS_ELEM);
        elem[items_s[tid]] = fmaxf(ssc[tid * 2] - ssc[tid * 2 + 1] + MARGIN, 0.f);
    }
}

__global__ __launch_bounds__(256) void reduce_mean_kernel(const int* __restrict__ ws,
                                                          float* __restrict__ out) {
    __shared__ float sred[4];
    const float* elem = (const float*)(ws + WS_ELEM);
    float s = 0.f;
    for (int i = threadIdx.x; i < NBATCH; i += 256) s += elem[i];
    s = wave_reduce(s);
    const int lane = threadIdx.x & 63;
    const int wv = threadIdx.x >> 6;
    if (lane == 0) sred[wv] = s;
    __syncthreads();
    if (threadIdx.x == 0)
        out[0] = (sred[0] + sred[1] + sred[2] + sred[3]) * (1.0f / (float)NBATCH);
}

extern "C" void kernel_launch(void* const* d_in, const int* in_sizes, int n_in,
                              void* d_out, int out_size, void* d_ws, size_t ws_size,
                              hipStream_t stream) {
    const int* pos_h = (const int*)d_in[0];
    const int* pos_t = (const int*)d_in[1];
    const int* pos_r = (const int*)d_in[2];
    const int* neg_h = (const int*)d_in[3];
    const int* neg_t = (const int*)d_in[4];
    const float* ent_emb = (const float*)d_in[5];
    const float* rel_emb = (const float*)d_in[6];
    const float* transfer = (const float*)d_in[7];

    int* ws = (int*)d_ws;
    float* out = (float*)d_out;

    zero_kernel<<<1, 1024, 0, stream>>>(ws);
    count_kernel<<<NBATCH / 256, 256, 0, stream>>>(pos_r, ws);
    scan_kernel<<<1, 1024, 0, stream>>>(ws);
    fill_kernel<<<NBATCH / 256, 256, 0, stream>>>(pos_r, ws);
    transr_chunk_kernel<<<MAXCHUNKS, 256, 0, stream>>>(
        pos_h, pos_t, neg_h, neg_t, ent_emb, rel_emb, transfer, ws);
    reduce_mean_kernel<<<1, 256, 0, stream>>>(ws, out);
}

// Round 3
// 418.681 us; speedup vs baseline: 1.5620x; 1.5620x over previous
//
#include <hip/hip_runtime.h>

#define ENT 200
#define RELD 200
#define NREL 1000
#define NBATCH 16384
#define MARGIN 4.0f
#define CHUNK 8        // items per block
#define NVEC 32        // CHUNK*4 vectors staged per block
#define MAXCHUNKS 3072 // >= 16384/8 + 1000 = 3048
#define SVPAD 36       // sv row stride: %4==0 (float4 align), %32==4 (8-way only on gather writes)

// ---- workspace layout (int units) ----
#define WS_COUNTS 0        // [1024]
#define WS_CURSORS 1024    // [1024]
#define WS_OFFSETS 2048    // [1024]
#define WS_NCHUNKS 3072    // [4]
#define WS_CHUNKS 3076     // int4[3072] -> 12288 ints (byte off 12304, 16B aligned)
#define WS_LIST 15364      // [16384]
#define WS_ELEM 31748      // float[16384]

__device__ __forceinline__ float wave_reduce(float v) {
#pragma unroll
    for (int off = 32; off > 0; off >>= 1) v += __shfl_down(v, off, 64);
    return v;
}

__global__ __launch_bounds__(1024) void zero_kernel(int* ws) {
    for (int i = threadIdx.x; i < 3076; i += 1024) ws[i] = 0;
}

__global__ __launch_bounds__(256) void count_kernel(const int* __restrict__ pos_r, int* ws) {
    const int i = blockIdx.x * 256 + threadIdx.x;
    if (i < NBATCH) atomicAdd(&ws[WS_COUNTS + pos_r[i]], 1);
}

// single block, 1024 threads: exclusive offsets + chunk descriptors
__global__ __launch_bounds__(1024) void scan_kernel(int* ws) {
    __shared__ int s[1024];
    const int tid = threadIdx.x;
    const int cnt = (tid < NREL) ? ws[WS_COUNTS + tid] : 0;
    s[tid] = cnt;
    __syncthreads();
#pragma unroll
    for (int off = 1; off < 1024; off <<= 1) {
        const int add = (tid >= off) ? s[tid - off] : 0;
        __syncthreads();
        s[tid] += add;
        __syncthreads();
    }
    const int myoff = s[tid] - cnt;
    if (tid < NREL) ws[WS_OFFSETS + tid] = myoff;
    __syncthreads();
    const int nch = (cnt + CHUNK - 1) / CHUNK;
    s[tid] = nch;
    __syncthreads();
#pragma unroll
    for (int off = 1; off < 1024; off <<= 1) {
        const int add = (tid >= off) ? s[tid - off] : 0;
        __syncthreads();
        s[tid] += add;
        __syncthreads();
    }
    const int cbase = s[tid] - nch;
    int4* chunks = (int4*)(ws + WS_CHUNKS);
    for (int k = 0; k < nch; ++k)
        chunks[cbase + k] = make_int4(tid, myoff + CHUNK * k, min(CHUNK, cnt - CHUNK * k), 0);
    if (tid == 1023) ws[WS_NCHUNKS] = s[1023];
}

__global__ __launch_bounds__(256) void fill_kernel(const int* __restrict__ pos_r, int* ws) {
    const int i = blockIdx.x * 256 + threadIdx.x;
    if (i < NBATCH) {
        const int r = pos_r[i];
        const int p = ws[WS_OFFSETS + r] + atomicAdd(&ws[WS_CURSORS + r], 1);
        ws[WS_LIST + p] = i;
    }
}

// One block (256 thr = 4 waves) per chunk of <=8 items sharing one relation.
// Wave w owns vecs 8w..8w+7 (= items 2w, 2w+1); lane = col-block (4 cols).
__global__ __launch_bounds__(256) void transr_chunk_kernel(
    const int* __restrict__ pos_h, const int* __restrict__ pos_t,
    const int* __restrict__ neg_h, const int* __restrict__ neg_t,
    const float* __restrict__ ent_emb, const float* __restrict__ rel_emb,
    const float* __restrict__ transfer, int* __restrict__ ws)
{
    const int nch = ws[WS_NCHUNKS];
    if ((int)blockIdx.x >= nch) return;

    __shared__ float sv[ENT][SVPAD];   // sv[e][vec]
    __shared__ int items_s[CHUNK];
    __shared__ int rows[NVEC];

    const int4 ck = ((const int4*)(ws + WS_CHUNKS))[blockIdx.x];
    const int r = ck.x, start = ck.y, cnt = ck.z;

    const int tid  = threadIdx.x;
    const int lane = tid & 63;
    const int wv   = tid >> 6;
    const bool valid = (lane < RELD / 4);            // 50 valid col-blocks
    const int c4 = (valid ? lane : (RELD / 4 - 1)) * 4;

    if (tid < CHUNK) items_s[tid] = ws[WS_LIST + start + min(tid, cnt - 1)];
    __syncthreads();
    if (tid < NVEC) {
        const int b = items_s[tid >> 2];
        const int c = tid & 3;
        rows[tid] = (c == 0) ? pos_h[b] : (c == 1) ? pos_t[b] : (c == 2) ? neg_h[b] : neg_t[b];
    }
    __syncthreads();

    // gather: wave w stages its own 8 vectors (coalesced global, scalar LDS writes)
#pragma unroll
    for (int k = 0; k < 8; ++k) {
        const int v = wv * 8 + k;
        const float* __restrict__ src = ent_emb + (size_t)rows[v] * ENT;
#pragma unroll
        for (int p = 0; p < 4; ++p) {
            const int e = lane + 64 * p;
            if (e < ENT) sv[e][v] = src[e];
        }
    }
    // relation row (per-lane 4 cols; identical across waves)
    float4 rl = *(const float4*)(rel_emb + (size_t)r * RELD + c4);
    if (!valid) rl = make_float4(0.f, 0.f, 0.f, 0.f);
    __syncthreads();

    const float* __restrict__ Mbase = transfer + (size_t)r * (ENT * RELD);

    float acc[8][4];
#pragma unroll
    for (int i = 0; i < 8; ++i)
#pragma unroll
        for (int c = 0; c < 4; ++c) acc[i][c] = 0.f;

#pragma unroll 2
    for (int e = 0; e < ENT; ++e) {
        const float4 m = *(const float4*)(Mbase + (size_t)e * RELD + c4);
        const float4* __restrict__ vr = (const float4*)(&sv[e][wv * 8]);
        const float4 va = vr[0];
        const float4 vb = vr[1];
        const float vs[8] = {va.x, va.y, va.z, va.w, vb.x, vb.y, vb.z, vb.w};
#pragma unroll
        for (int i = 0; i < 8; ++i) {
            acc[i][0] = fmaf(vs[i], m.x, acc[i][0]);
            acc[i][1] = fmaf(vs[i], m.y, acc[i][1]);
            acc[i][2] = fmaf(vs[i], m.z, acc[i][2]);
            acc[i][3] = fmaf(vs[i], m.w, acc[i][3]);
        }
    }
    if (!valid) {
#pragma unroll
        for (int i = 0; i < 8; ++i)
#pragma unroll
            for (int c = 0; c < 4; ++c) acc[i][c] = 0.f;
    }

    // ---- wave-local epilogue ----
    // relation inverse norm (redundantly per wave; no sync needed)
    float rs = rl.x * rl.x + rl.y * rl.y + rl.z * rl.z + rl.w * rl.w;
    rs = __shfl(wave_reduce(rs), 0);
    const float rinv = rsqrtf(fmaxf(rs, 1e-12f));

    float inv[8];
#pragma unroll
    for (int i = 0; i < 8; ++i) {
        float s = acc[i][0] * acc[i][0] + acc[i][1] * acc[i][1] +
                  acc[i][2] * acc[i][2] + acc[i][3] * acc[i][3];
        s = __shfl(wave_reduce(s), 0);
        inv[i] = rsqrtf(fmaxf(s, 1e-12f));
    }

    const float rlv[4] = {rl.x * rinv, rl.y * rinv, rl.z * rinv, rl.w * rinv};
    float* elem = (float*)(ws + WS_ELEM);
#pragma unroll
    for (int it = 0; it < 2; ++it) {
        const int base = it * 4;  // vecs: +0=h, +1=t, +2=nh, +3=nt
        float p = 0.f, n = 0.f;
#pragma unroll
        for (int c = 0; c < 4; ++c) {
            const float ph = acc[base + 0][c] * inv[base + 0];
            const float pt = acc[base + 1][c] * inv[base + 1];
            const float xh = acc[base + 2][c] * inv[base + 2];
            const float xt = acc[base + 3][c] * inv[base + 3];
            p += fabsf(ph + rlv[c] - pt);
            n += fabsf(xh + rlv[c] - xt);
        }
        p = wave_reduce(p);
        n = wave_reduce(n);
        const int ii = 2 * wv + it;
        if (lane == 0 && ii < cnt)
            elem[items_s[ii]] = fmaxf(p - n + MARGIN, 0.f);
    }
}

__global__ __launch_bounds__(256) void reduce_mean_kernel(const int* __restrict__ ws,
                                                          float* __restrict__ out) {
    __shared__ float sred[4];
    const float4* elem = (const float4*)(ws + WS_ELEM);
    float s = 0.f;
    for (int i = threadIdx.x; i < NBATCH / 4; i += 256) {
        const float4 v = elem[i];
        s += v.x + v.y + v.z + v.w;
    }
    s = wave_reduce(s);
    const int lane = threadIdx.x & 63;
    const int wvv = threadIdx.x >> 6;
    if (lane == 0) sred[wvv] = s;
    __syncthreads();
    if (threadIdx.x == 0)
        out[0] = (sred[0] + sred[1] + sred[2] + sred[3]) * (1.0f / (float)NBATCH);
}

extern "C" void kernel_launch(void* const* d_in, const int* in_sizes, int n_in,
                              void* d_out, int out_size, void* d_ws, size_t ws_size,
                              hipStream_t stream) {
    const int* pos_h = (const int*)d_in[0];
    const int* pos_t = (const int*)d_in[1];
    const int* pos_r = (const int*)d_in[2];
    const int* neg_h = (const int*)d_in[3];
    const int* neg_t = (const int*)d_in[4];
    const float* ent_emb = (const float*)d_in[5];
    const float* rel_emb = (const float*)d_in[6];
    const float* transfer = (const float*)d_in[7];

    int* ws = (int*)d_ws;
    float* out = (float*)d_out;

    zero_kernel<<<1, 1024, 0, stream>>>(ws);
    count_kernel<<<NBATCH / 256, 256, 0, stream>>>(pos_r, ws);
    scan_kernel<<<1, 1024, 0, stream>>>(ws);
    fill_kernel<<<NBATCH / 256, 256, 0, stream>>>(pos_r, ws);
    transr_chunk_kernel<<<MAXCHUNKS, 256, 0, stream>>>(
        pos_h, pos_t, neg_h, neg_t, ent_emb, rel_emb, transfer, ws);
    reduce_mean_kernel<<<1, 256, 0, stream>>>(ws, out);
}

// Round 4
// 311.417 us; speedup vs baseline: 2.1001x; 1.3444x over previous
//
#include <hip/hip_runtime.h>

#define ENT 200
#define RELD 200
#define NREL 1000
#define NBATCH 16384
#define MARGIN 4.0f
#define CHUNK 16
#define NVEC 64
#define MAXCHUNKS 2048   // >= 16384/16 + 1000 = 2024

// B-fragment LDS layout: 16B slot = buf*BBUF + i*BSTRIDE_I + w
//   w = q*52 + c*4 + np  (writer thread slot, 0..207), i = col&3
// write: lanes stride-1 (conflict-free); read: <=2-way (free, m136)
#define BSTRIDE_I 211
#define BBUF 844

// ---- workspace layout (int units) ----
#define WS_COUNTS 0        // [1024]
#define WS_CURSORS 1024    // [1024]
#define WS_OFFSETS 2048    // [1024]
#define WS_NCHUNKS 3072    // [4]
#define WS_CHUNKS 3076     // int4[2048]
#define WS_LIST 11268      // [16384]
#define WS_ELEM 27652      // float[16384] (byte off 110608, 16B aligned)

typedef __attribute__((ext_vector_type(8))) short short8;
typedef __attribute__((ext_vector_type(4))) float floatx4;

__device__ __forceinline__ unsigned short f2bf(float x) {
    unsigned u = __float_as_uint(x);
    u = (u + 0x7FFFu + ((u >> 16) & 1u)) >> 16;   // RNE
    return (unsigned short)u;
}

__device__ __forceinline__ float wave_reduce(float v) {
#pragma unroll
    for (int off = 32; off > 0; off >>= 1) v += __shfl_down(v, off, 64);
    return v;
}

__global__ __launch_bounds__(1024) void zero_kernel(int* ws) {
    for (int i = threadIdx.x; i < 3076; i += 1024) ws[i] = 0;
}

__global__ __launch_bounds__(256) void count_kernel(const int* __restrict__ pos_r, int* ws) {
    const int i = blockIdx.x * 256 + threadIdx.x;
    if (i < NBATCH) atomicAdd(&ws[WS_COUNTS + pos_r[i]], 1);
}

__global__ __launch_bounds__(1024) void scan_kernel(int* ws) {
    __shared__ int s[1024];
    const int tid = threadIdx.x;
    const int cnt = (tid < NREL) ? ws[WS_COUNTS + tid] : 0;
    s[tid] = cnt;
    __syncthreads();
#pragma unroll
    for (int off = 1; off < 1024; off <<= 1) {
        const int add = (tid >= off) ? s[tid - off] : 0;
        __syncthreads();
        s[tid] += add;
        __syncthreads();
    }
    const int myoff = s[tid] - cnt;
    if (tid < NREL) ws[WS_OFFSETS + tid] = myoff;
    __syncthreads();
    const int nch = (cnt + CHUNK - 1) / CHUNK;
    s[tid] = nch;
    __syncthreads();
#pragma unroll
    for (int off = 1; off < 1024; off <<= 1) {
        const int add = (tid >= off) ? s[tid - off] : 0;
        __syncthreads();
        s[tid] += add;
        __syncthreads();
    }
    const int cbase = s[tid] - nch;
    int4* chunks = (int4*)(ws + WS_CHUNKS);
    for (int k = 0; k < nch; ++k)
        chunks[cbase + k] = make_int4(tid, myoff + CHUNK * k, min(CHUNK, cnt - CHUNK * k), 0);
    if (tid == 1023) ws[WS_NCHUNKS] = s[1023];
}

__global__ __launch_bounds__(256) void fill_kernel(const int* __restrict__ pos_r, int* ws) {
    const int i = blockIdx.x * 256 + threadIdx.x;
    if (i < NBATCH) {
        const int r = pos_r[i];
        const int p = ws[WS_OFFSETS + r] + atomicAdd(&ws[WS_CURSORS + r], 1);
        ws[WS_LIST + p] = i;
    }
}

// One block (4 waves) per chunk of <=16 items sharing one relation matrix.
// Wave R owns row-tile R (16 vecs = 4 items). Lane (q=lane>>4, n=lane&15):
// D[row=q*4+reg][col=c*16+n] -> item R*4+q, component reg: epilogue is in-lane.
__global__ __launch_bounds__(256) void transr_mfma_kernel(
    const int* __restrict__ pos_h, const int* __restrict__ pos_t,
    const int* __restrict__ neg_h, const int* __restrict__ neg_t,
    const float* __restrict__ ent_emb, const float* __restrict__ rel_emb,
    const float* __restrict__ transfer, int* __restrict__ ws)
{
    const int nch = ws[WS_NCHUNKS];
    if ((int)blockIdx.x >= nch) return;

    __shared__ short sB[2 * BBUF * 8];   // 27008 B, double-buffered B-fragments
    __shared__ int items_s[CHUNK];
    __shared__ int rows[NVEC];

    const int4 ck = ((const int4*)(ws + WS_CHUNKS))[blockIdx.x];
    const int r = ck.x, start = ck.y, cnt = ck.z;

    const int tid  = threadIdx.x;
    const int lane = tid & 63;
    const int wv   = tid >> 6;      // row-tile R
    const int q    = lane >> 4;
    const int n    = lane & 15;

    if (tid < CHUNK) items_s[tid] = ws[WS_LIST + start + min(tid, cnt - 1)];
    __syncthreads();
    if (tid < NVEC) {
        const int b = items_s[tid >> 2];
        const int c = tid & 3;
        rows[tid] = (c == 0) ? pos_h[b] : (c == 1) ? pos_t[b] : (c == 2) ? neg_h[b] : neg_t[b];
    }
    __syncthreads();

    // relation values for this lane's columns (fp32, kept exact for epilogue)
    float rl[13];
    {
        const float* __restrict__ rb = rel_emb + (size_t)r * RELD;
#pragma unroll
        for (int c = 0; c < 13; ++c) {
            const int col = c * 16 + n;
            rl[c] = (col < RELD) ? rb[col] : 0.f;
        }
    }

    // A fragments in registers: afrag[s], lane m=n is tile row, k = s*32 + q*8 + j
    short8 afrag[7];
    {
        const int row = rows[wv * 16 + n];
        const float* __restrict__ ab = ent_emb + (size_t)row * ENT;
#pragma unroll
        for (int s = 0; s < 7; ++s) {
            const int e0 = s * 32 + q * 8;
            short8 f = {0, 0, 0, 0, 0, 0, 0, 0};
            if (e0 < ENT) {
                float v[8];
                *(float4*)(&v[0]) = *(const float4*)(ab + e0);
                *(float4*)(&v[4]) = *(const float4*)(ab + e0 + 4);
#pragma unroll
                for (int j = 0; j < 8; ++j) f[j] = (short)f2bf(v[j]);
            }
            afrag[s] = f;
        }
    }

    // B staging: thread slot -> (q, col-block, 4-col group); reads M columns,
    // writes packed fragments stride-1 into LDS.
    const int slot = tid;
    const int sq   = slot / 52;
    const int srem = slot - sq * 52;
    const int sc   = srem >> 2;
    const int snp  = srem & 3;
    const int scol = sc * 16 + snp * 4;
    const bool sact = (slot < 208) && (scol < RELD);
    const float* __restrict__ Mb = transfer + (size_t)r * (ENT * RELD) + scol;

    float fm[8][4];
#define LOAD_SLAB(s_)                                                          \
    {                                                                          \
        const int k0 = (s_) * 32 + sq * 8;                                     \
        if (sact && k0 < ENT) {                                                \
            _Pragma("unroll")                                                  \
            for (int j = 0; j < 8; ++j)                                        \
                *(float4*)(&fm[j][0]) = *(const float4*)(Mb + (size_t)(k0 + j) * RELD); \
        } else {                                                               \
            _Pragma("unroll")                                                  \
            for (int j = 0; j < 8; ++j) {                                      \
                fm[j][0] = 0.f; fm[j][1] = 0.f; fm[j][2] = 0.f; fm[j][3] = 0.f;\
            }                                                                  \
        }                                                                      \
    }
#define COMMIT_SLAB(buf_)                                                      \
    if (slot < 208) {                                                          \
        _Pragma("unroll")                                                      \
        for (int i = 0; i < 4; ++i) {                                          \
            short8 f;                                                          \
            _Pragma("unroll")                                                  \
            for (int j = 0; j < 8; ++j) f[j] = (short)f2bf(fm[j][i]);          \
            *(short8*)(&sB[((buf_) * BBUF + i * BSTRIDE_I + slot) * 8]) = f;   \
        }                                                                      \
    }

    floatx4 acc[13];
#pragma unroll
    for (int c = 0; c < 13; ++c) acc[c] = (floatx4){0.f, 0.f, 0.f, 0.f};

    const int rb16 = (n & 3) * BSTRIDE_I + q * 52 + (n >> 2);  // + c*4 + buf*BBUF

    LOAD_SLAB(0);
    COMMIT_SLAB(0);
    __syncthreads();

#pragma unroll
    for (int s = 0; s < 7; ++s) {
        if (s < 6) LOAD_SLAB(s + 1);           // global loads in flight over MFMAs
        const int bb = (s & 1) * BBUF;
#pragma unroll
        for (int c = 0; c < 13; ++c) {
            const short8 bf = *(const short8*)(&sB[(bb + rb16 + c * 4) * 8]);
            acc[c] = __builtin_amdgcn_mfma_f32_16x16x32_bf16(afrag[s], bf, acc[c], 0, 0, 0);
        }
        if (s < 6) {
            COMMIT_SLAB((s + 1) & 1);
            __syncthreads();
        }
    }

    // ---- in-lane epilogue ----
    float nsq[4] = {0.f, 0.f, 0.f, 0.f};
    float rsq = 0.f;
#pragma unroll
    for (int c = 0; c < 13; ++c) {
        nsq[0] += acc[c][0] * acc[c][0];
        nsq[1] += acc[c][1] * acc[c][1];
        nsq[2] += acc[c][2] * acc[c][2];
        nsq[3] += acc[c][3] * acc[c][3];
        rsq += rl[c] * rl[c];
    }
#pragma unroll
    for (int m = 1; m < 16; m <<= 1) {
#pragma unroll
        for (int k = 0; k < 4; ++k) nsq[k] += __shfl_xor(nsq[k], m, 64);
        rsq += __shfl_xor(rsq, m, 64);
    }
    float inv[4];
#pragma unroll
    for (int k = 0; k < 4; ++k) inv[k] = rsqrtf(fmaxf(nsq[k], 1e-12f));
    const float invr = rsqrtf(fmaxf(rsq, 1e-12f));

    float psum = 0.f, nsum = 0.f;
#pragma unroll
    for (int c = 0; c < 13; ++c) {
        const float rr = rl[c] * invr;
        psum += fabsf(acc[c][0] * inv[0] + rr - acc[c][1] * inv[1]);
        nsum += fabsf(acc[c][2] * inv[2] + rr - acc[c][3] * inv[3]);
    }
#pragma unroll
    for (int m = 1; m < 16; m <<= 1) {
        psum += __shfl_xor(psum, m, 64);
        nsum += __shfl_xor(nsum, m, 64);
    }
    const int item = wv * 4 + q;
    if (n == 0 && item < cnt) {
        float* elem = (float*)(ws + WS_ELEM);
        elem[items_s[item]] = fmaxf(psum - nsum + MARGIN, 0.f);
    }
}

__global__ __launch_bounds__(256) void reduce_mean_kernel(const int* __restrict__ ws,
                                                          float* __restrict__ out) {
    __shared__ float sred[4];
    const float4* elem = (const float4*)(ws + WS_ELEM);
    float s = 0.f;
    for (int i = threadIdx.x; i < NBATCH / 4; i += 256) {
        const float4 v = elem[i];
        s += v.x + v.y + v.z + v.w;
    }
    s = wave_reduce(s);
    const int lane = threadIdx.x & 63;
    const int wvv = threadIdx.x >> 6;
    if (lane == 0) sred[wvv] = s;
    __syncthreads();
    if (threadIdx.x == 0)
        out[0] = (sred[0] + sred[1] + sred[2] + sred[3]) * (1.0f / (float)NBATCH);
}

extern "C" void kernel_launch(void* const* d_in, const int* in_sizes, int n_in,
                              void* d_out, int out_size, void* d_ws, size_t ws_size,
                              hipStream_t stream) {
    const int* pos_h = (const int*)d_in[0];
    const int* pos_t = (const int*)d_in[1];
    const int* pos_r = (const int*)d_in[2];
    const int* neg_h = (const int*)d_in[3];
    const int* neg_t = (const int*)d_in[4];
    const float* ent_emb = (const float*)d_in[5];
    const float* rel_emb = (const float*)d_in[6];
    const float* transfer = (const float*)d_in[7];

    int* ws = (int*)d_ws;
    float* out = (float*)d_out;

    zero_kernel<<<1, 1024, 0, stream>>>(ws);
    count_kernel<<<NBATCH / 256, 256, 0, stream>>>(pos_r, ws);
    scan_kernel<<<1, 1024, 0, stream>>>(ws);
    fill_kernel<<<NBATCH / 256, 256, 0, stream>>>(pos_r, ws);
    transr_mfma_kernel<<<MAXCHUNKS, 256, 0, stream>>>(
        pos_h, pos_t, neg_h, neg_t, ent_emb, rel_emb, transfer, ws);
    reduce_mean_kernel<<<1, 256, 0, stream>>>(ws, out);
}

// Round 5
// 311.032 us; speedup vs baseline: 2.1027x; 1.0012x over previous
//
#include <hip/hip_runtime.h>

#define ENT 200
#define RELD 200
#define NREL 1000
#define NBATCH 16384
#define MARGIN 4.0f
#define CHUNK 32
#define NVEC 128
#define MAXCHUNKS 1536   // >= 16384/32 + 1000 = 1512

// B-fragment LDS layout (verified in R4): 16B slot = buf*BBUF + i*BSTRIDE_I + w
//   w = writer slot (0..207) = sq*52 + sc*4 + snp, i = col&3
#define BSTRIDE_I 211
#define BBUF 844

// ---- workspace layout (int units) ----
#define WS_COUNTS 0        // [1024]
#define WS_CURSORS 1024    // [1024]
#define WS_OFFSETS 2048    // [1024]
#define WS_NCHUNKS 3072    // [4]
#define WS_CHUNKS 3076     // int4[1536] -> 6144 ints (byte 12304, 16B aligned)
#define WS_LIST 9220       // [16384]
#define WS_ELEM 25604      // float[16384] (byte 102416, 16B aligned)

typedef __attribute__((ext_vector_type(8))) short short8;
typedef __attribute__((ext_vector_type(4))) short short4v;
typedef __attribute__((ext_vector_type(4))) float floatx4;

__device__ __forceinline__ unsigned short f2bf(float x) {
    unsigned u = __float_as_uint(x);
    u = (u + 0x7FFFu + ((u >> 16) & 1u)) >> 16;   // RNE
    return (unsigned short)u;
}

__device__ __forceinline__ float wave_reduce(float v) {
#pragma unroll
    for (int off = 32; off > 0; off >>= 1) v += __shfl_down(v, off, 64);
    return v;
}

__global__ __launch_bounds__(1024) void zero_kernel(int* ws) {
    for (int i = threadIdx.x; i < 3076; i += 1024) ws[i] = 0;
}

__global__ __launch_bounds__(256) void count_kernel(const int* __restrict__ pos_r, int* ws) {
    const int i = blockIdx.x * 256 + threadIdx.x;
    if (i < NBATCH) atomicAdd(&ws[WS_COUNTS + pos_r[i]], 1);
}

__global__ __launch_bounds__(1024) void scan_kernel(int* ws) {
    __shared__ int s[1024];
    const int tid = threadIdx.x;
    const int cnt = (tid < NREL) ? ws[WS_COUNTS + tid] : 0;
    s[tid] = cnt;
    __syncthreads();
#pragma unroll
    for (int off = 1; off < 1024; off <<= 1) {
        const int add = (tid >= off) ? s[tid - off] : 0;
        __syncthreads();
        s[tid] += add;
        __syncthreads();
    }
    const int myoff = s[tid] - cnt;
    if (tid < NREL) ws[WS_OFFSETS + tid] = myoff;
    __syncthreads();
    const int nch = (cnt + CHUNK - 1) / CHUNK;
    s[tid] = nch;
    __syncthreads();
#pragma unroll
    for (int off = 1; off < 1024; off <<= 1) {
        const int add = (tid >= off) ? s[tid - off] : 0;
        __syncthreads();
        s[tid] += add;
        __syncthreads();
    }
    const int cbase = s[tid] - nch;
    int4* chunks = (int4*)(ws + WS_CHUNKS);
    for (int k = 0; k < nch; ++k)
        chunks[cbase + k] = make_int4(tid, myoff + CHUNK * k, min(CHUNK, cnt - CHUNK * k), 0);
    if (tid == 1023) ws[WS_NCHUNKS] = s[1023];
}

__global__ __launch_bounds__(256) void fill_kernel(const int* __restrict__ pos_r, int* ws) {
    const int i = blockIdx.x * 256 + threadIdx.x;
    if (i < NBATCH) {
        const int r = pos_r[i];
        const int p = ws[WS_OFFSETS + r] + atomicAdd(&ws[WS_CURSORS + r], 1);
        ws[WS_LIST + p] = i;
    }
}

// One block (512 thr = 8 waves) per chunk of <=32 items sharing one relation.
// Wave R owns row-tile R (16 vecs = 4 items); all waves share the B fragments.
// Lane (q=lane>>4, n=lane&15): D[row=q*4+reg][col=c*16+n] -> item R*4+q 4-comp in-lane.
__global__ __launch_bounds__(512, 4) void transr_mfma_kernel(
    const int* __restrict__ pos_h, const int* __restrict__ pos_t,
    const int* __restrict__ neg_h, const int* __restrict__ neg_t,
    const float* __restrict__ ent_emb, const float* __restrict__ rel_emb,
    const float* __restrict__ transfer, int* __restrict__ ws)
{
    const int nch = ws[WS_NCHUNKS];
    if ((int)blockIdx.x >= nch) return;

    __shared__ short sB[2 * BBUF * 8];   // 27008 B, double-buffered B-fragments
    __shared__ int items_s[CHUNK];
    __shared__ int rows[NVEC];

    const int4 ck = ((const int4*)(ws + WS_CHUNKS))[blockIdx.x];
    const int r = ck.x, start = ck.y, cnt = ck.z;

    const int tid  = threadIdx.x;
    const int lane = tid & 63;
    const int wv   = tid >> 6;      // row-tile 0..7
    const int q    = lane >> 4;
    const int n    = lane & 15;

    if (tid < CHUNK) items_s[tid] = ws[WS_LIST + start + min(tid, cnt - 1)];
    __syncthreads();
    if (tid < NVEC) {
        const int b = items_s[tid >> 2];
        const int c = tid & 3;
        rows[tid] = (c == 0) ? pos_h[b] : (c == 1) ? pos_t[b] : (c == 2) ? neg_h[b] : neg_t[b];
    }
    __syncthreads();

    // A fragments in registers: lane row m=n, k = s*32 + q*8 + j
    short8 afrag[7];
    {
        const int row = rows[wv * 16 + n];
        const float* __restrict__ ab = ent_emb + (size_t)row * ENT;
#pragma unroll
        for (int s = 0; s < 7; ++s) {
            const int e0 = s * 32 + q * 8;
            short8 f = {0, 0, 0, 0, 0, 0, 0, 0};
            if (e0 < ENT) {
                float v[8];
                *(float4*)(&v[0]) = *(const float4*)(ab + e0);
                *(float4*)(&v[4]) = *(const float4*)(ab + e0 + 4);
#pragma unroll
                for (int j = 0; j < 8; ++j) f[j] = (short)f2bf(v[j]);
            }
            afrag[s] = f;
        }
    }

    // B staging: thread -> (slot, h): slot=tid>>1 (0..207 for tid<416), h=tid&1.
    // Slot covers 4 cols scol..scol+3, rows k0 = sq*8 + h*4 .. +3 per slab.
    const int slot = tid >> 1;
    const int h    = tid & 1;
    const int sq   = slot / 52;
    const int srem = slot - sq * 52;
    const int scol = srem * 4;               // == (srem>>2)*16 + (srem&3)*4
    const bool sact = (tid < 416) && (scol < RELD);
    const float* __restrict__ Mb = transfer + (size_t)r * (ENT * RELD) + scol;
    const int k0 = sq * 8 + h * 4;

    float fm[4][4];
#define LOAD_SLAB(s_)                                                          \
    {                                                                          \
        const int kk = (s_) * 32 + k0;                                         \
        if (sact && kk < ENT) {                                                \
            _Pragma("unroll")                                                  \
            for (int j = 0; j < 4; ++j)                                        \
                *(float4*)(&fm[j][0]) = *(const float4*)(Mb + (size_t)(kk + j) * RELD); \
        } else {                                                               \
            _Pragma("unroll")                                                  \
            for (int j = 0; j < 4; ++j) {                                      \
                fm[j][0] = 0.f; fm[j][1] = 0.f; fm[j][2] = 0.f; fm[j][3] = 0.f;\
            }                                                                  \
        }                                                                      \
    }
#define COMMIT_SLAB(buf_)                                                      \
    if (tid < 416) {                                                           \
        _Pragma("unroll")                                                      \
        for (int i = 0; i < 4; ++i) {                                          \
            short4v f;                                                         \
            _Pragma("unroll")                                                  \
            for (int j = 0; j < 4; ++j) f[j] = (short)f2bf(fm[j][i]);          \
            *(short4v*)(&sB[((buf_) * BBUF + i * BSTRIDE_I + slot) * 8 + h * 4]) = f; \
        }                                                                      \
    }

    floatx4 acc[13];
#pragma unroll
    for (int c = 0; c < 13; ++c) acc[c] = (floatx4){0.f, 0.f, 0.f, 0.f};

    const int rb16 = (n & 3) * BSTRIDE_I + q * 52 + (n >> 2);  // + c*4 + buf*BBUF

    LOAD_SLAB(0);
    COMMIT_SLAB(0);
    __syncthreads();

#pragma unroll
    for (int s = 0; s < 7; ++s) {
        if (s < 6) LOAD_SLAB(s + 1);           // next-slab loads in flight over MFMAs
        const int bb = (s & 1) * BBUF;
#pragma unroll
        for (int c = 0; c < 13; ++c) {
            const short8 bf = *(const short8*)(&sB[(bb + rb16 + c * 4) * 8]);
            acc[c] = __builtin_amdgcn_mfma_f32_16x16x32_bf16(afrag[s], bf, acc[c], 0, 0, 0);
        }
        if (s < 6) {
            COMMIT_SLAB((s + 1) & 1);
            __syncthreads();
        }
    }

    // ---- in-lane epilogue (rl loaded late: short live range) ----
    float rl[13];
    {
        const float* __restrict__ rb = rel_emb + (size_t)r * RELD;
#pragma unroll
        for (int c = 0; c < 13; ++c) {
            const int col = c * 16 + n;
            rl[c] = (col < RELD) ? rb[col] : 0.f;
        }
    }
    float nsq[4] = {0.f, 0.f, 0.f, 0.f};
    float rsq = 0.f;
#pragma unroll
    for (int c = 0; c < 13; ++c) {
        nsq[0] += acc[c][0] * acc[c][0];
        nsq[1] += acc[c][1] * acc[c][1];
        nsq[2] += acc[c][2] * acc[c][2];
        nsq[3] += acc[c][3] * acc[c][3];
        rsq += rl[c] * rl[c];
    }
#pragma unroll
    for (int m = 1; m < 16; m <<= 1) {
#pragma unroll
        for (int k = 0; k < 4; ++k) nsq[k] += __shfl_xor(nsq[k], m, 64);
        rsq += __shfl_xor(rsq, m, 64);
    }
    float inv[4];
#pragma unroll
    for (int k = 0; k < 4; ++k) inv[k] = rsqrtf(fmaxf(nsq[k], 1e-12f));
    const float invr = rsqrtf(fmaxf(rsq, 1e-12f));

    float psum = 0.f, nsum = 0.f;
#pragma unroll
    for (int c = 0; c < 13; ++c) {
        const float rr = rl[c] * invr;
        psum += fabsf(acc[c][0] * inv[0] + rr - acc[c][1] * inv[1]);
        nsum += fabsf(acc[c][2] * inv[2] + rr - acc[c][3] * inv[3]);
    }
#pragma unroll
    for (int m = 1; m < 16; m <<= 1) {
        psum += __shfl_xor(psum, m, 64);
        nsum += __shfl_xor(nsum, m, 64);
    }
    const int item = wv * 4 + q;
    if (n == 0 && item < cnt) {
        float* elem = (float*)(ws + WS_ELEM);
        elem[items_s[item]] = fmaxf(psum - nsum + MARGIN, 0.f);
    }
}

__global__ __launch_bounds__(256) void reduce_mean_kernel(const int* __restrict__ ws,
                                                          float* __restrict__ out) {
    __shared__ float sred[4];
    const float4* elem = (const float4*)(ws + WS_ELEM);
    float s = 0.f;
    for (int i = threadIdx.x; i < NBATCH / 4; i += 256) {
        const float4 v = elem[i];
        s += v.x + v.y + v.z + v.w;
    }
    s = wave_reduce(s);
    const int lane = threadIdx.x & 63;
    const int wvv = threadIdx.x >> 6;
    if (lane == 0) sred[wvv] = s;
    __syncthreads();
    if (threadIdx.x == 0)
        out[0] = (sred[0] + sred[1] + sred[2] + sred[3]) * (1.0f / (float)NBATCH);
}

extern "C" void kernel_launch(void* const* d_in, const int* in_sizes, int n_in,
                              void* d_out, int out_size, void* d_ws, size_t ws_size,
                              hipStream_t stream) {
    const int* pos_h = (const int*)d_in[0];
    const int* pos_t = (const int*)d_in[1];
    const int* pos_r = (const int*)d_in[2];
    const int* neg_h = (const int*)d_in[3];
    const int* neg_t = (const int*)d_in[4];
    const float* ent_emb = (const float*)d_in[5];
    const float* rel_emb = (const float*)d_in[6];
    const float* transfer = (const float*)d_in[7];

    int* ws = (int*)d_ws;
    float* out = (float*)d_out;

    zero_kernel<<<1, 1024, 0, stream>>>(ws);
    count_kernel<<<NBATCH / 256, 256, 0, stream>>>(pos_r, ws);
    scan_kernel<<<1, 1024, 0, stream>>>(ws);
    fill_kernel<<<NBATCH / 256, 256, 0, stream>>>(pos_r, ws);
    transr_mfma_kernel<<<MAXCHUNKS, 512, 0, stream>>>(
        pos_h, pos_t, neg_h, neg_t, ent_emb, rel_emb, transfer, ws);
    reduce_mean_kernel<<<1, 256, 0, stream>>>(ws, out);
}

// Round 6
// 309.242 us; speedup vs baseline: 2.1149x; 1.0058x over previous
//
#include <hip/hip_runtime.h>

#define ENT 200
#define RELD 200
#define NREL 1000
#define NBATCH 16384
#define MARGIN 4.0f
#define CHUNK 16
#define NVEC 64
#define MAXCHUNKS 2048   // >= 16384/16 + 1000 = 2024

// B-fragment LDS layout (verified R4): 16B slot index = buf*BBUF + i*BSTRIDE_I + w
//   w = writer slot (0..207) = sq*52 + sc*4 + snp, i = col&3
#define BSTRIDE_I 211
#define BBUF 844

// ---- workspace layout (int units) ----
#define WS_COUNTS 0        // [1024]
#define WS_CURSORS 1024    // [1024]
#define WS_OFFSETS 2048    // [1024]
#define WS_NCHUNKS 3072    // [4]
#define WS_CHUNKS 3076     // int4[2048]
#define WS_LIST 11268      // [16384]
#define WS_ELEM 27652      // float[16384] (byte 110608, 16B aligned)

typedef __attribute__((ext_vector_type(8))) short short8;
typedef __attribute__((ext_vector_type(4))) float floatx4;

__device__ __forceinline__ unsigned short f2bf(float x) {
    unsigned u = __float_as_uint(x);
    u = (u + 0x7FFFu + ((u >> 16) & 1u)) >> 16;   // RNE
    return (unsigned short)u;
}

__device__ __forceinline__ float wave_reduce(float v) {
#pragma unroll
    for (int off = 32; off > 0; off >>= 1) v += __shfl_down(v, off, 64);
    return v;
}

__global__ __launch_bounds__(1024) void zero_kernel(int* ws) {
    for (int i = threadIdx.x; i < 3076; i += 1024) ws[i] = 0;
}

__global__ __launch_bounds__(256) void count_kernel(const int* __restrict__ pos_r, int* ws) {
    const int i = blockIdx.x * 256 + threadIdx.x;
    if (i < NBATCH) atomicAdd(&ws[WS_COUNTS + pos_r[i]], 1);
}

__global__ __launch_bounds__(1024) void scan_kernel(int* ws) {
    __shared__ int s[1024];
    const int tid = threadIdx.x;
    const int cnt = (tid < NREL) ? ws[WS_COUNTS + tid] : 0;
    s[tid] = cnt;
    __syncthreads();
#pragma unroll
    for (int off = 1; off < 1024; off <<= 1) {
        const int add = (tid >= off) ? s[tid - off] : 0;
        __syncthreads();
        s[tid] += add;
        __syncthreads();
    }
    const int myoff = s[tid] - cnt;
    if (tid < NREL) ws[WS_OFFSETS + tid] = myoff;
    __syncthreads();
    const int nch = (cnt + CHUNK - 1) / CHUNK;
    s[tid] = nch;
    __syncthreads();
#pragma unroll
    for (int off = 1; off < 1024; off <<= 1) {
        const int add = (tid >= off) ? s[tid - off] : 0;
        __syncthreads();
        s[tid] += add;
        __syncthreads();
    }
    const int cbase = s[tid] - nch;
    int4* chunks = (int4*)(ws + WS_CHUNKS);
    for (int k = 0; k < nch; ++k)
        chunks[cbase + k] = make_int4(tid, myoff + CHUNK * k, min(CHUNK, cnt - CHUNK * k), 0);
    if (tid == 1023) ws[WS_NCHUNKS] = s[1023];
}

__global__ __launch_bounds__(256) void fill_kernel(const int* __restrict__ pos_r, int* ws) {
    const int i = blockIdx.x * 256 + threadIdx.x;
    if (i < NBATCH) {
        const int r = pos_r[i];
        const int p = ws[WS_OFFSETS + r] + atomicAdd(&ws[WS_CURSORS + r], 1);
        ws[WS_LIST + p] = i;
    }
}

// One block (256 thr = 4 waves) per chunk of <=16 items sharing one relation.
// XCD-contiguous swizzle: XCD x (blockIdx%8) owns chunks [x*stride,(x+1)*stride)
// so the 2 chunks of one relation run adjacently on the SAME XCD -> 2nd M read
// hits that XCD's L2 instead of L3/HBM.
__global__ __launch_bounds__(256) void transr_mfma_kernel(
    const int* __restrict__ pos_h, const int* __restrict__ pos_t,
    const int* __restrict__ neg_h, const int* __restrict__ neg_t,
    const float* __restrict__ ent_emb, const float* __restrict__ rel_emb,
    const float* __restrict__ transfer, int* __restrict__ ws)
{
    const int nch = ws[WS_NCHUNKS];
    const int stride = (nch + 7) >> 3;
    const int bidx = blockIdx.x;
    if ((bidx >> 3) >= stride) return;
    const int cix = (bidx & 7) * stride + (bidx >> 3);
    if (cix >= nch) return;

    __shared__ short sB[2 * BBUF * 8];   // 27008 B double-buffered B-fragments
    __shared__ int items_s[CHUNK];
    __shared__ int rows[NVEC];

    const int4 ck = ((const int4*)(ws + WS_CHUNKS))[cix];
    const int r = ck.x, start = ck.y, cnt = ck.z;

    const int tid  = threadIdx.x;
    const int lane = tid & 63;
    const int wv   = tid >> 6;      // row-tile 0..3
    const int q    = lane >> 4;
    const int n    = lane & 15;
    const bool wactive = (wv * 4 < cnt);   // wave's items: wv*4 .. wv*4+3

    if (tid < CHUNK) items_s[tid] = ws[WS_LIST + start + min(tid, cnt - 1)];
    __syncthreads();
    if (tid < NVEC) {
        const int b = items_s[tid >> 2];
        const int c = tid & 3;
        rows[tid] = (c == 0) ? pos_h[b] : (c == 1) ? pos_t[b] : (c == 2) ? neg_h[b] : neg_t[b];
    }
    __syncthreads();

    // A fragments in registers (active waves only): lane row m=n, k = s*32+q*8+j
    short8 afrag[7];
#pragma unroll
    for (int s = 0; s < 7; ++s) afrag[s] = (short8){0, 0, 0, 0, 0, 0, 0, 0};
    if (wactive) {
        const int row = rows[wv * 16 + n];
        const float* __restrict__ ab = ent_emb + (size_t)row * ENT;
#pragma unroll
        for (int s = 0; s < 7; ++s) {
            const int e0 = s * 32 + q * 8;
            if (e0 < ENT) {
                float v[8];
                *(float4*)(&v[0]) = *(const float4*)(ab + e0);
                *(float4*)(&v[4]) = *(const float4*)(ab + e0 + 4);
                short8 f;
#pragma unroll
                for (int j = 0; j < 8; ++j) f[j] = (short)f2bf(v[j]);
                afrag[s] = f;
            }
        }
    }

    // B staging: slot=tid (0..207 active), covers 4 cols x 8 rows per slab.
    const int slot = tid;
    const int sq   = slot / 52;
    const int srem = slot - sq * 52;
    const int scol = srem * 4;
    const bool sact = (slot < 208) && (scol < RELD);
    const float* __restrict__ Mb = transfer + (size_t)r * (ENT * RELD) + scol;
    const int k0 = sq * 8;

    float fm[8][4];     // in-flight fp32 slab
    short8 bh[4];       // converted slab awaiting commit
#define LOAD_SLAB(s_)                                                          \
    {                                                                          \
        const int kk = (s_) * 32 + k0;                                         \
        if (sact && kk < ENT) {                                                \
            _Pragma("unroll")                                                  \
            for (int j = 0; j < 8; ++j)                                        \
                *(float4*)(&fm[j][0]) = *(const float4*)(Mb + (size_t)(kk + j) * RELD); \
        } else {                                                               \
            _Pragma("unroll")                                                  \
            for (int j = 0; j < 8; ++j) {                                      \
                fm[j][0] = 0.f; fm[j][1] = 0.f; fm[j][2] = 0.f; fm[j][3] = 0.f;\
            }                                                                  \
        }                                                                      \
    }
#define CONV_SLAB()                                                            \
    {                                                                          \
        _Pragma("unroll")                                                      \
        for (int i = 0; i < 4; ++i) {                                          \
            short8 f;                                                          \
            _Pragma("unroll")                                                  \
            for (int j = 0; j < 8; ++j) f[j] = (short)f2bf(fm[j][i]);          \
            bh[i] = f;                                                         \
        }                                                                      \
    }
#define WRITE_SLAB(buf_)                                                       \
    if (slot < 208) {                                                          \
        _Pragma("unroll")                                                      \
        for (int i = 0; i < 4; ++i)                                            \
            *(short8*)(&sB[((buf_) * BBUF + i * BSTRIDE_I + slot) * 8]) = bh[i]; \
    }

    floatx4 acc[13];
#pragma unroll
    for (int c = 0; c < 13; ++c) acc[c] = (floatx4){0.f, 0.f, 0.f, 0.f};

    const int rb16 = (n & 3) * BSTRIDE_I + q * 52 + (n >> 2);  // + c*4 + buf*BBUF

    // pipeline preamble: buf0 <- slab0; bh <- slab1
    LOAD_SLAB(0); CONV_SLAB(); WRITE_SLAB(0);
    LOAD_SLAB(1); CONV_SLAB();
    __syncthreads();

#pragma unroll
    for (int s = 0; s < 7; ++s) {
        if (s < 5) LOAD_SLAB(s + 2);           // loads in flight over MFMA + write
        if (wactive) {
            const int bb = (s & 1) * BBUF;
#pragma unroll
            for (int c = 0; c < 13; ++c) {
                const short8 bf = *(const short8*)(&sB[(bb + rb16 + c * 4) * 8]);
                acc[c] = __builtin_amdgcn_mfma_f32_16x16x32_bf16(afrag[s], bf, acc[c], 0, 0, 0);
            }
        }
        if (s < 6) WRITE_SLAB((s + 1) & 1);    // bh still holds slab s+1
        if (s < 5) CONV_SLAB();                // fm(s+2) -> bh, vmcnt covered by MFMA+write
        if (s < 6) __syncthreads();
    }

    // ---- in-lane epilogue (active waves only) ----
    if (wactive) {
        float rl[13];
        const float* __restrict__ rb = rel_emb + (size_t)r * RELD;
#pragma unroll
        for (int c = 0; c < 13; ++c) {
            const int col = c * 16 + n;
            rl[c] = (col < RELD) ? rb[col] : 0.f;
        }
        float nsq[4] = {0.f, 0.f, 0.f, 0.f};
        float rsq = 0.f;
#pragma unroll
        for (int c = 0; c < 13; ++c) {
            nsq[0] += acc[c][0] * acc[c][0];
            nsq[1] += acc[c][1] * acc[c][1];
            nsq[2] += acc[c][2] * acc[c][2];
            nsq[3] += acc[c][3] * acc[c][3];
            rsq += rl[c] * rl[c];
        }
#pragma unroll
        for (int m = 1; m < 16; m <<= 1) {
#pragma unroll
            for (int k = 0; k < 4; ++k) nsq[k] += __shfl_xor(nsq[k], m, 64);
            rsq += __shfl_xor(rsq, m, 64);
        }
        float inv[4];
#pragma unroll
        for (int k = 0; k < 4; ++k) inv[k] = rsqrtf(fmaxf(nsq[k], 1e-12f));
        const float invr = rsqrtf(fmaxf(rsq, 1e-12f));

        float psum = 0.f, nsum = 0.f;
#pragma unroll
        for (int c = 0; c < 13; ++c) {
            const float rr = rl[c] * invr;
            psum += fabsf(acc[c][0] * inv[0] + rr - acc[c][1] * inv[1]);
            nsum += fabsf(acc[c][2] * inv[2] + rr - acc[c][3] * inv[3]);
        }
#pragma unroll
        for (int m = 1; m < 16; m <<= 1) {
            psum += __shfl_xor(psum, m, 64);
            nsum += __shfl_xor(nsum, m, 64);
        }
        const int item = wv * 4 + q;
        if (n == 0 && item < cnt) {
            float* elem = (float*)(ws + WS_ELEM);
            elem[items_s[item]] = fmaxf(psum - nsum + MARGIN, 0.f);
        }
    }
}

__global__ __launch_bounds__(256) void reduce_mean_kernel(const int* __restrict__ ws,
                                                          float* __restrict__ out) {
    __shared__ float sred[4];
    const float4* elem = (const float4*)(ws + WS_ELEM);
    float s = 0.f;
    for (int i = threadIdx.x; i < NBATCH / 4; i += 256) {
        const float4 v = elem[i];
        s += v.x + v.y + v.z + v.w;
    }
    s = wave_reduce(s);
    const int lane = threadIdx.x & 63;
    const int wvv = threadIdx.x >> 6;
    if (lane == 0) sred[wvv] = s;
    __syncthreads();
    if (threadIdx.x == 0)
        out[0] = (sred[0] + sred[1] + sred[2] + sred[3]) * (1.0f / (float)NBATCH);
}

extern "C" void kernel_launch(void* const* d_in, const int* in_sizes, int n_in,
                              void* d_out, int out_size, void* d_ws, size_t ws_size,
                              hipStream_t stream) {
    const int* pos_h = (const int*)d_in[0];
    const int* pos_t = (const int*)d_in[1];
    const int* pos_r = (const int*)d_in[2];
    const int* neg_h = (const int*)d_in[3];
    const int* neg_t = (const int*)d_in[4];
    const float* ent_emb = (const float*)d_in[5];
    const float* rel_emb = (const float*)d_in[6];
    const float* transfer = (const float*)d_in[7];

    int* ws = (int*)d_ws;
    float* out = (float*)d_out;

    zero_kernel<<<1, 1024, 0, stream>>>(ws);
    count_kernel<<<NBATCH / 256, 256, 0, stream>>>(pos_r, ws);
    scan_kernel<<<1, 1024, 0, stream>>>(ws);
    fill_kernel<<<NBATCH / 256, 256, 0, stream>>>(pos_r, ws);
    transr_mfma_kernel<<<MAXCHUNKS, 256, 0, stream>>>(
        pos_h, pos_t, neg_h, neg_t, ent_emb, rel_emb, transfer, ws);
    reduce_mean_kernel<<<1, 256, 0, stream>>>(ws, out);
}